// Round 5
// baseline (1127.352 us; speedup 1.0000x reference)
//
#include <hip/hip_runtime.h>

#define NB 8
#define NN 8192
#define NC 32
#define NPOINT 1024
#define NSAMPLE 32

// Exact round-to-nearest distance, no fma contraction: matches numpy
// ((dx*dx + dy*dy) + dz*dz) bitwise.
__device__ __forceinline__ float d2_exact(float ax, float ay, float az,
                                          float bx, float by, float bz) {
    float dx = __fsub_rn(ax, bx);
    float dy = __fsub_rn(ay, by);
    float dz = __fsub_rn(az, bz);
    return __fadd_rn(__fadd_rn(__fmul_rn(dx, dx), __fmul_rn(dy, dy)),
                     __fmul_rn(dz, dz));
}

// ---------------------------------------------------------------------------
// Round-8: producer is ISSUE-BOUND (round-0 standalone fps: VALUBusy 68% of
// the 8 producer CUs => ~775 wave-instrs issued per 2270-cyc iteration, vs
// ~435 in source). This round cuts issued instructions:
//   (1) packed-fp32 distance update (v_pk_add/v_pk_mul, bitwise-exact dual
//       IEEE-rn ops — ALREADY checker-verified in round 1): 8 instr / 2
//       points instead of 16. At 256 threads / 1 wave/SIMD the issue cut
//       translates 1:1 into time (round-1's 512-thread test couldn't show
//       this: 2 waves/SIMD share one issue port).
//   (2) 32-bit dual-phase wave reduce instead of emulated 64-bit DPP max:
//       6x v_max_f32-DPP (fused modifier, 1 instr/stage), readlane(63)
//       broadcast, then cand=(bvf==wmax)?bp:~0u and 6x v_min_u32-DPP with
//       old=-1 fill => exact min-p among max-holders = first-occurrence.
//       No +-0/NaN hazards: all dists are >= +0. Lane 63 rebuilds the same
//       (bits(wmax)<<32)|~minp key for the unchanged cross-wave combine.
//   (3) publish every iteration (single relaxed agent-scope atomic from
//       tid 0; <=1 outstanding store per ~2000-cyc iter; LDS-only barrier
//       never drains it) — removes the 16-iter frontier lag from the
//       consumer tail.
// Kept: fused producer/consumer structure, LDS-staged coords for the
// winner fetch, LDS-only in-loop barrier, 4-chain argmax scan, f64-max
// cross-wave combine, plain launch + memset init.
// ---------------------------------------------------------------------------
#define FPS_T 256
#define FPS_K (NN / FPS_T)   // 32 points per thread
#define NCONS 248
#define NBLK (NB + NCONS)    // 256 blocks, 1 per CU
#define K2_WAVES 4
#define SLOTS_PER_PASS (NCONS * K2_WAVES)                              // 992
#define NPASS ((NB * NPOINT + SLOTS_PER_PASS - 1) / SLOTS_PER_PASS)    // 9

#define XS 37   // X row stride (35 cols + pad)
#define HS 65   // H row stride (64 cols + pad)

// shared-memory union layout (bytes):
//   producer: redk[2][4] ull @0 (64), sel_hist[1024] int @64 (4096),
//             sxyz[8192*3] f32 @4160 (98304)  -> 102464 used
//   consumer: sel_s[4][32] int @0 (512), bufA[4][2080] f32 @512 (33280),
//             bufB[4][2080] f32 @33792 (33280) -> 67072 used
// 102464 > 81920 guarantees 1 block/CU (2 blocks would exceed 160 KB).
#define SMEM_BYTES 102464

typedef float f32x2 __attribute__((ext_vector_type(2)));

// Packed dual-FP32 ops: two independent IEEE round-to-nearest f32 ops per
// instruction (VOP3P). Exactness == __fadd_rn/__fmul_rn (checker-verified
// bitwise in round 1). Halves of an f32x2 are plain VGPRs: extraction free.
__device__ __forceinline__ f32x2 pk_add(f32x2 a, f32x2 b) {
    f32x2 d;
    asm("v_pk_add_f32 %0, %1, %2" : "=v"(d) : "v"(a), "v"(b));
    return d;
}
__device__ __forceinline__ f32x2 pk_mul(f32x2 a, f32x2 b) {
    f32x2 d;
    asm("v_pk_mul_f32 %0, %1, %2" : "=v"(d) : "v"(a), "v"(b));
    return d;
}

// u64 max implemented as v_max_f64 — valid for our key domain: high word is
// f32 bits of a dist in [0, 1e10] => non-negative finite f64 pattern, where
// u64 order == f64 order (denormals included; f64 never flushes).
__device__ __forceinline__ unsigned long long kmax64(unsigned long long a,
                                                     unsigned long long b) {
    double r = fmax(__longlong_as_double((long long)a),
                    __longlong_as_double((long long)b));
    return (unsigned long long)__double_as_longlong(r);
}

// f32 DPP step, zero-fill (identity for max over values >= +0).
template <int CTRL, int RM>
__device__ __forceinline__ float dpp_f(float x) {
    return __int_as_float(__builtin_amdgcn_update_dpp(
        0, __float_as_int(x), CTRL, RM, 0xf, true));
}
// u32 DPP step, old=-1 fill (identity for unsigned min).
template <int CTRL, int RM>
__device__ __forceinline__ unsigned dpp_u(unsigned x) {
    return (unsigned)__builtin_amdgcn_update_dpp(
        -1, (int)x, CTRL, RM, 0xf, false);
}

// Workgroup barrier that drains LDS ops only (no vmcnt(0)): keeps the
// fire-and-forget publish atomics off the barrier critical path.
__device__ __forceinline__ void barrier_lds_only() {
    asm volatile("s_waitcnt lgkmcnt(0)\n\ts_barrier" ::: "memory");
}

__global__ __launch_bounds__(256, 1) void fused_kernel(
    const float* __restrict__ xyz, const float* __restrict__ normal,
    const float* __restrict__ features,
    const float* __restrict__ w1, const float* __restrict__ b1,
    const float* __restrict__ w2, const float* __restrict__ b2,
    const float* __restrict__ w3, const float* __restrict__ b3,
    float* __restrict__ out_xyz, float* __restrict__ out_normal,
    float* __restrict__ out_feat, int* __restrict__ idxbuf) {

    __shared__ __align__(16) char smem[SMEM_BYTES];

    if (blockIdx.x < NB) {
        // ================= producer: FPS ===================================
        unsigned long long (*redk)[4] = (unsigned long long (*)[4])(smem);
        int*   sel_hist = (int*)(smem + 64);
        float* sxyz     = (float*)(smem + 64 + 4096);

        const int b = blockIdx.x;
        const float* bx = xyz + (size_t)b * NN * 3;
        const int tid = threadIdx.x;
        const int lane = tid & 63;
        const int wave = tid >> 6;   // 0..3
        int* idxg = idxbuf + (b << 10);

        // Interleaved pair layout: pair q holds point k=2q in .x (low VGPR)
        // and k=2q+1 in .y (high VGPR). p = tid + k*FPS_T.
        f32x2 px[FPS_K / 2], py[FPS_K / 2], pz[FPS_K / 2];
        float dist[FPS_K];
#pragma unroll
        for (int k = 0; k < FPS_K; ++k) {
            int p = tid + k * FPS_T;
            float x = bx[p * 3 + 0];
            float y = bx[p * 3 + 1];
            float z = bx[p * 3 + 2];
            sxyz[p * 3 + 0] = x;
            sxyz[p * 3 + 1] = y;
            sxyz[p * 3 + 2] = z;
            if ((k & 1) == 0) { px[k >> 1].x = x; py[k >> 1].x = y; pz[k >> 1].x = z; }
            else              { px[k >> 1].y = x; py[k >> 1].y = y; pz[k >> 1].y = z; }
            dist[k] = 1e10f;
        }
        // Pin the packed coordinate arrays (pre-loop only): opaque asm stops
        // the compiler from sinking the global loads into the hot loop.
#pragma unroll
        for (int q = 0; q < FPS_K / 2; ++q) {
            asm volatile("" : "+v"(px[q]), "+v"(py[q]), "+v"(pz[q]));
        }

        int cur = 0;
        float lx = bx[0], ly = bx[1], lz = bx[2];

        for (int it = 0; it < NPOINT; ++it) {
            const int par = it & 1;
            if (tid == 0) {
                sel_hist[it] = cur;
                // publish immediately: consumers see centroid `it` with zero
                // frontier lag. Relaxed agent atomic, never drained in-loop.
                __hip_atomic_store(idxg + it, cur, __ATOMIC_RELAXED,
                                   __HIP_MEMORY_SCOPE_AGENT);
            }

            // a - b == a + (-b) exactly in IEEE; pk_add(p, -l) == fsub_rn.
            f32x2 nlx = {-lx, -lx};
            f32x2 nly = {-ly, -ly};
            f32x2 nlz = {-lz, -lz};

            // 4 independent argmax chains over contiguous k-ranges (chain c
            // owns k in [8c, 8c+8) => dep depth 8). Lower chain owns lower
            // k; strict > at every combine keeps first occurrence.
            float bv[4] = {-1.0f, -1.0f, -1.0f, -1.0f};
            int bk[4] = {0, 0, 0, 0};
#pragma unroll
            for (int q = 0; q < FPS_K / 2; ++q) {
                const int c = q >> 2;
                f32x2 dx = pk_add(px[q], nlx);
                f32x2 dy = pk_add(py[q], nly);
                f32x2 dz = pk_add(pz[q], nlz);
                // ((dx*dx + dy*dy) + dz*dz) with separate mul/add — no fma.
                f32x2 d2 = pk_add(pk_add(pk_mul(dx, dx), pk_mul(dy, dy)),
                                  pk_mul(dz, dz));
                float nd0 = fminf(dist[2 * q + 0], d2.x);
                float nd1 = fminf(dist[2 * q + 1], d2.y);
                dist[2 * q + 0] = nd0;
                dist[2 * q + 1] = nd1;
                bool g0 = nd0 > bv[c];      // strict >: lowest k on ties
                bv[c] = g0 ? nd0 : bv[c];
                bk[c] = g0 ? 2 * q + 0 : bk[c];
                bool g1 = nd1 > bv[c];
                bv[c] = g1 ? nd1 : bv[c];
                bk[c] = g1 ? 2 * q + 1 : bk[c];
            }
            bool g1 = bv[1] > bv[0];
            float v01 = g1 ? bv[1] : bv[0];
            int   k01 = g1 ? bk[1] : bk[0];
            bool g3 = bv[3] > bv[2];
            float v23 = g3 ? bv[3] : bv[2];
            int   k23 = g3 ? bk[3] : bk[2];
            bool gf = v23 > v01;
            float bvf = gf ? v23 : v01;
            int   bkf = gf ? k23 : k01;

            int bp = tid + (bkf << 8);      // global point index (FPS_T==256)

            // ---- phase 1: wave max of the distance (f32, DPP-fused) ------
            float wm = bvf;                 // bvf >= +0 always
            wm = fmaxf(wm, dpp_f<0x111, 0xf>(wm));
            wm = fmaxf(wm, dpp_f<0x112, 0xf>(wm));
            wm = fmaxf(wm, dpp_f<0x114, 0xf>(wm));
            wm = fmaxf(wm, dpp_f<0x118, 0xf>(wm));
            wm = fmaxf(wm, dpp_f<0x142, 0xa>(wm));
            wm = fmaxf(wm, dpp_f<0x143, 0xc>(wm));   // lane 63 holds wave max
            float wmax = __int_as_float(
                __builtin_amdgcn_readlane(__float_as_int(wm), 63));

            // ---- phase 2: min point-index among max-holders --------------
            // Exact ==: all dists >= +0 (no -0), max result is bit-equal to
            // one of the inputs. Non-holders contribute u32-max (identity).
            unsigned cand = (bvf == wmax) ? (unsigned)bp : 0xFFFFFFFFu;
            cand = min(cand, dpp_u<0x111, 0xf>(cand));
            cand = min(cand, dpp_u<0x112, 0xf>(cand));
            cand = min(cand, dpp_u<0x114, 0xf>(cand));
            cand = min(cand, dpp_u<0x118, 0xf>(cand));
            cand = min(cand, dpp_u<0x142, 0xa>(cand));
            cand = min(cand, dpp_u<0x143, 0xc>(cand)); // lane 63: wave min-p

            if (lane == 63) {
                unsigned long long key =
                    ((unsigned long long)__float_as_uint(wmax) << 32) |
                    (unsigned)(~cand);
                redk[par][wave] = key;
            }
            barrier_lds_only();

            unsigned long long g =
                kmax64(kmax64(redk[par][0], redk[par][1]),
                       kmax64(redk[par][2], redk[par][3]));
            int p = (int)(~(unsigned)(g & 0xffffffffULL));
            p = __builtin_amdgcn_readfirstlane(p);   // uniform
            // winner coords from LDS broadcast (uniform addr) — keeps the
            // L2 round trip off the serial path.
            lx = sxyz[p * 3 + 0];
            ly = sxyz[p * 3 + 1];
            lz = sxyz[p * 3 + 2];
            cur = p;
        }
        __syncthreads();

        // final gather of new_xyz / new_normal (host-visible outputs)
        const float* bn = normal + (size_t)b * NN * 3;
        for (int t = tid; t < NPOINT; t += FPS_T) {
            int i = sel_hist[t];
            size_t o = ((size_t)b * NPOINT + t) * 3;
            out_xyz[o + 0] = sxyz[i * 3 + 0];
            out_xyz[o + 1] = sxyz[i * 3 + 1];
            out_xyz[o + 2] = sxyz[i * 3 + 2];
            out_normal[o + 0] = bn[i * 3 + 0];
            out_normal[o + 1] = bn[i * 3 + 1];
            out_normal[o + 2] = bn[i * 3 + 2];
        }
    } else {
        // ================= consumer: ball query + MLP + maxpool ============
        int*   sel_all  = (int*)smem;                    // [4][32]
        float* bufA_all = (float*)(smem + 512);          // [4][2080]
        float* bufB_all = (float*)(smem + 33792);        // [4][2080]

        const int cb = blockIdx.x - NB;      // 0..247
        const int wave = threadIdx.x >> 6;   // 0..3
        const int lane = threadIdx.x & 63;
        int*   sel = sel_all + wave * 32;
        float* XA  = bufA_all + wave * 2080;
        float* XB  = bufB_all + wave * 2080;

        for (int pass = 0; pass < NPASS; ++pass) {
            int k = pass * SLOTS_PER_PASS + (cb * K2_WAVES + wave);
            if (k >= NB * NPOINT) k -= NB * NPOINT;  // dummies redo early
                                                     // centroids (identical
                                                     // rewrites: benign)
            const int b = k & 7;
            const int t = k >> 3;
            const int g = (b << 10) + t;
            const int p = t;
            const float* bxp = xyz + (size_t)b * NN * 3;
            const float* bfp = features + (size_t)b * NN * NC;

            // wait until the producer has published this centroid's index
            int v = __hip_atomic_load(idxbuf + g, __ATOMIC_RELAXED,
                                      __HIP_MEMORY_SCOPE_AGENT);
            while (v < 0) {
                __builtin_amdgcn_s_sleep(8);
                v = __hip_atomic_load(idxbuf + g, __ATOMIC_RELAXED,
                                      __HIP_MEMORY_SCOPE_AGENT);
            }
            const float cx = bxp[v * 3 + 0];
            const float cy = bxp[v * 3 + 1];
            const float cz = bxp[v * 3 + 2];

            // ---- ball query: first NSAMPLE hits in ascending index order --
            int have = 0;
            for (int ch = 0; ch < NN / 64 && have < NSAMPLE; ++ch) {
                int j = ch * 64 + lane;
                float x = bxp[j * 3 + 0], y = bxp[j * 3 + 1], z = bxp[j * 3 + 2];
                float d2 = d2_exact(x, y, z, cx, cy, cz);
                bool hit = d2 < 0.04f;   // strict f32 compare
                unsigned long long m = __ballot(hit);
                int pos = have + __popcll(m & ((1ull << lane) - 1ull));
                if (hit && pos < NSAMPLE) sel[pos] = j;
                have += __popcll(m);
            }
            __syncthreads();
            int nsel = have < NSAMPLE ? have : NSAMPLE;
            int first = sel[0];   // centroid itself always hits -> nsel >= 1
            if (lane < NSAMPLE && lane >= nsel) sel[lane] = first;
            __syncthreads();

            // ---- gather X = [rel_xyz(3) | features(32)] into LDS ----------
            {
                int s = lane >> 1, h = lane & 1;
                int row = sel[s];
                const float* fr = bfp + (size_t)row * NC + h * 16;
#pragma unroll
                for (int q = 0; q < 4; ++q) {
                    float4 vv = *(const float4*)(fr + q * 4);
                    int base = s * XS + 3 + h * 16 + q * 4;
                    XA[base + 0] = vv.x; XA[base + 1] = vv.y;
                    XA[base + 2] = vv.z; XA[base + 3] = vv.w;
                }
                if (h == 0) {
                    XA[s * XS + 0] = __fsub_rn(bxp[row * 3 + 0], cx);
                    XA[s * XS + 1] = __fsub_rn(bxp[row * 3 + 1], cy);
                    XA[s * XS + 2] = __fsub_rn(bxp[row * 3 + 2], cz);
                }
            }
            __syncthreads();

            const int sg = lane >> 3;   // 0..7 -> samples sg*4 .. sg*4+3
            const int og = lane & 7;    // output-channel group

            // ---- layer 1: 35 -> 64 ---------------------------------------
            {
                float acc[4][8];
#pragma unroll
                for (int j = 0; j < 4; ++j)
#pragma unroll
                    for (int o = 0; o < 8; ++o) acc[j][o] = 0.f;
                for (int c = 0; c < 35; ++c) {
                    float xv[4];
#pragma unroll
                    for (int j = 0; j < 4; ++j) xv[j] = XA[(sg * 4 + j) * XS + c];
                    const float* wr = w1 + c * 64 + og * 8;
                    float4 wa = *(const float4*)(wr);
                    float4 wb = *(const float4*)(wr + 4);
                    float w8[8] = {wa.x, wa.y, wa.z, wa.w, wb.x, wb.y, wb.z, wb.w};
#pragma unroll
                    for (int j = 0; j < 4; ++j)
#pragma unroll
                        for (int o = 0; o < 8; ++o) acc[j][o] += xv[j] * w8[o];
                }
                float4 ba = *(const float4*)(b1 + og * 8);
                float4 bb = *(const float4*)(b1 + og * 8 + 4);
                float bias[8] = {ba.x, ba.y, ba.z, ba.w, bb.x, bb.y, bb.z, bb.w};
#pragma unroll
                for (int j = 0; j < 4; ++j)
#pragma unroll
                    for (int o = 0; o < 8; ++o)
                        XB[(sg * 4 + j) * HS + og * 8 + o] =
                            fmaxf(acc[j][o] + bias[o], 0.f);
            }
            __syncthreads();

            // ---- layer 2: 64 -> 64 ---------------------------------------
            {
                float acc[4][8];
#pragma unroll
                for (int j = 0; j < 4; ++j)
#pragma unroll
                    for (int o = 0; o < 8; ++o) acc[j][o] = 0.f;
                for (int c = 0; c < 64; ++c) {
                    float xv[4];
#pragma unroll
                    for (int j = 0; j < 4; ++j) xv[j] = XB[(sg * 4 + j) * HS + c];
                    const float* wr = w2 + c * 64 + og * 8;
                    float4 wa = *(const float4*)(wr);
                    float4 wb = *(const float4*)(wr + 4);
                    float w8[8] = {wa.x, wa.y, wa.z, wa.w, wb.x, wb.y, wb.z, wb.w};
#pragma unroll
                    for (int j = 0; j < 4; ++j)
#pragma unroll
                        for (int o = 0; o < 8; ++o) acc[j][o] += xv[j] * w8[o];
                }
                float4 ba = *(const float4*)(b2 + og * 8);
                float4 bb = *(const float4*)(b2 + og * 8 + 4);
                float bias[8] = {ba.x, ba.y, ba.z, ba.w, bb.x, bb.y, bb.z, bb.w};
#pragma unroll
                for (int j = 0; j < 4; ++j)
#pragma unroll
                    for (int o = 0; o < 8; ++o)
                        XA[(sg * 4 + j) * HS + og * 8 + o] =
                            fmaxf(acc[j][o] + bias[o], 0.f);
            }
            __syncthreads();

            // ---- layer 3: 64 -> 128, maxpool over 32 samples -------------
            {
                float acc[4][16];
#pragma unroll
                for (int j = 0; j < 4; ++j)
#pragma unroll
                    for (int o = 0; o < 16; ++o) acc[j][o] = 0.f;
                for (int c = 0; c < 64; ++c) {
                    float xv[4];
#pragma unroll
                    for (int j = 0; j < 4; ++j) xv[j] = XA[(sg * 4 + j) * HS + c];
                    const float* wr = w3 + c * 128 + og * 16;
                    float4 wq[4];
#pragma unroll
                    for (int q = 0; q < 4; ++q) wq[q] = *(const float4*)(wr + q * 4);
                    float w16[16] = {wq[0].x, wq[0].y, wq[0].z, wq[0].w,
                                     wq[1].x, wq[1].y, wq[1].z, wq[1].w,
                                     wq[2].x, wq[2].y, wq[2].z, wq[2].w,
                                     wq[3].x, wq[3].y, wq[3].z, wq[3].w};
#pragma unroll
                    for (int j = 0; j < 4; ++j)
#pragma unroll
                        for (int o = 0; o < 16; ++o) acc[j][o] += xv[j] * w16[o];
                }
                float m[16];
#pragma unroll
                for (int o = 0; o < 16; ++o) {
                    float t0 = fmaxf(acc[0][o], acc[1][o]);
                    float t1 = fmaxf(acc[2][o], acc[3][o]);
                    m[o] = fmaxf(t0, t1);
                }
#pragma unroll
                for (int off = 8; off <= 32; off <<= 1)
#pragma unroll
                    for (int o = 0; o < 16; ++o)
                        m[o] = fmaxf(m[o], __shfl_xor(m[o], off));
                if (sg == 0) {
                    float4 bq[4];
#pragma unroll
                    for (int q = 0; q < 4; ++q)
                        bq[q] = *(const float4*)(b3 + og * 16 + q * 4);
                    float bias[16] = {bq[0].x, bq[0].y, bq[0].z, bq[0].w,
                                      bq[1].x, bq[1].y, bq[1].z, bq[1].w,
                                      bq[2].x, bq[2].y, bq[2].z, bq[2].w,
                                      bq[3].x, bq[3].y, bq[3].z, bq[3].w};
#pragma unroll
                    for (int o = 0; o < 16; ++o) {
                        float val = fmaxf(m[o] + bias[o], 0.f);
                        out_feat[((size_t)b * 128 + og * 16 + o) * NPOINT + p] = val;
                    }
                }
            }
            // bufA reread next pass only after the pass's early barriers.
        }
    }
}

// ---------------------------------------------------------------------------
extern "C" void kernel_launch(void* const* d_in, const int* in_sizes, int n_in,
                              void* d_out, int out_size, void* d_ws, size_t ws_size,
                              hipStream_t stream) {
    const float* xyz      = (const float*)d_in[0];
    const float* normal   = (const float*)d_in[1];
    const float* features = (const float*)d_in[2];
    const float* w1 = (const float*)d_in[3];
    const float* b1 = (const float*)d_in[4];
    const float* w2 = (const float*)d_in[5];
    const float* b2 = (const float*)d_in[6];
    const float* w3 = (const float*)d_in[7];
    const float* b3 = (const float*)d_in[8];

    float* out        = (float*)d_out;
    float* out_xyz    = out;                       // (8,1024,3)
    float* out_normal = out + NB * NPOINT * 3;     // (8,1024,3)
    float* out_feat   = out + 2 * NB * NPOINT * 3; // (8,128,1024)
    int*   idxbuf     = (int*)d_ws;                // 8192 ints

    // 0xFF bytes -> every int == -1 (the "unpublished" sentinel).
    hipMemsetAsync(idxbuf, 0xFF, NB * NPOINT * sizeof(int), stream);

    hipLaunchKernelGGL(fused_kernel, dim3(NBLK), dim3(256), 0, stream,
                       xyz, normal, features, w1, b1, w2, b2, w3, b3,
                       out_xyz, out_normal, out_feat, idxbuf);
}

// Round 6
// 1025.990 us; speedup vs baseline: 1.0988x; 1.0988x over previous
//
#include <hip/hip_runtime.h>

#define NB 8
#define NN 8192
#define NC 32
#define NPOINT 1024
#define NSAMPLE 32

// Exact round-to-nearest distance, no fma contraction: matches numpy
// ((dx*dx + dy*dy) + dz*dz) bitwise.
__device__ __forceinline__ float d2_exact(float ax, float ay, float az,
                                          float bx, float by, float bz) {
    float dx = __fsub_rn(ax, bx);
    float dy = __fsub_rn(ay, by);
    float dz = __fsub_rn(az, bz);
    return __fadd_rn(__fadd_rn(__fmul_rn(dx, dx), __fmul_rn(dy, dy)),
                     __fmul_rn(dz, dz));
}

// ---------------------------------------------------------------------------
// Round-9: producer loop is byte-identical to round-4 (best measured: fused
// 970us / total 1025us). Rounds 1/3/5 proved every producer micro-change
// (pk math, in-loop pins, reduce rewrites) regresses — v_pk_f32 is a 2-pass
// op on gfx950 (157 TF peak already assumes plain f32 rate), so packing cuts
// instructions but not cycles. Producer is retired as optimized.
//
// This round cuts the measured ~55us consumer TAIL instead: the last ~256
// centroids publish at ~890-915us and each was processed by a single wave at
// ~33us/centroid. Now:
//   - bulk phase: 8 exact passes x 992 wave-slots = 7936 centroids
//     (wave-per-centroid, unchanged code, no wrap/dummy work);
//   - final 256 centroids: ONE BLOCK EACH, 4-wave cooperative (wave 0 does
//     ball query; gather/MLP split samples across 256 threads; maxpool via
//     shfl tree + 4-way LDS combine). Producers JOIN consumption after their
//     gather (block b takes centroid (b, t=1023) — the one it published
//     itself moments earlier), giving 256 blocks for 256 final centroids.
//     Per-centroid latency ~33us -> ~11us.
// Per-(sample,channel) accumulation chains and c-order are identical to the
// wave-per-centroid path => bitwise-identical outputs (fmax reassociation
// only affects +-0 sign, invisible to absmax).
// ---------------------------------------------------------------------------
#define FPS_T 256
#define FPS_K (NN / FPS_T)   // 32 points per thread
#define NCONS 248
#define NBLK (NB + NCONS)    // 256 blocks, 1 per CU
#define K2_WAVES 4
#define SLOTS_PER_PASS (NCONS * K2_WAVES)   // 992
#define NBULK 8                             // 8*992 = 7936 bulk centroids
#define NFINAL (NB * NPOINT - NBULK * SLOTS_PER_PASS)   // 256

#define XS 37   // X row stride (35 cols + pad)
#define HS 65   // H row stride (64 cols + pad)

// shared-memory union layout (bytes):
//   producer: redk[2][4] ull @0 (64), sel_hist[1024] int @64 (4096),
//             sxyz[8192*3] f32 @4160 (98304)  -> 102464 used
//   consumer bulk: sel[4][32] int @0 (512), bufA[4][2080] f32 @512,
//             bufB[4][2080] f32 @33792 -> 67072 used
//   coop tail: sel[32] int @0, X/H2[2080] f32 @512 (bufA region),
//             H1[2080] f32 @33792 (bufB), pmax[4][128] f32 @33792+8320
// 102464 > 81920 guarantees 1 block/CU.
#define SMEM_BYTES 102464

// u64 max implemented as v_max_f64 — valid for our key domain: high word is
// f32 bits of a dist in [0, 1e10] => non-negative finite f64 pattern, where
// u64 order == f64 order (denormals included; f64 never flushes).
__device__ __forceinline__ unsigned long long kmax64(unsigned long long a,
                                                     unsigned long long b) {
    double r = fmax(__longlong_as_double((long long)a),
                    __longlong_as_double((long long)b));
    return (unsigned long long)__double_as_longlong(r);
}

template <int CTRL, int RM>
__device__ __forceinline__ unsigned long long dpp_k(unsigned long long k) {
    unsigned hi = (unsigned)__builtin_amdgcn_update_dpp(
        0, (int)(k >> 32), CTRL, RM, 0xf, true);
    unsigned lo = (unsigned)__builtin_amdgcn_update_dpp(
        0, (int)(k & 0xffffffffULL), CTRL, RM, 0xf, true);
    return ((unsigned long long)hi << 32) | lo;
}

// Workgroup barrier that drains LDS ops only (no vmcnt(0)): keeps the
// fire-and-forget publish atomics off the barrier critical path.
__device__ __forceinline__ void barrier_lds_only() {
    asm volatile("s_waitcnt lgkmcnt(0)\n\ts_barrier" ::: "memory");
}

// ---------------------------------------------------------------------------
// Block-cooperative (256-thread) ball-query + MLP + maxpool for ONE centroid.
// Same formulas / accumulation order as the wave-per-centroid path: sample =
// tid>>3 (one per thread), og = tid&7. Used for the final-256 tail phase.
// ---------------------------------------------------------------------------
__device__ void coop_centroid(
    int b, int t, const float* __restrict__ xyz,
    const float* __restrict__ features,
    const float* __restrict__ w1, const float* __restrict__ b1,
    const float* __restrict__ w2, const float* __restrict__ b2,
    const float* __restrict__ w3, const float* __restrict__ b3,
    float* __restrict__ out_feat, int* __restrict__ idxbuf,
    char* smem, int tid) {
    const int wave = tid >> 6;
    const int lane = tid & 63;
    int*   sel  = (int*)smem;                          // 32 ints
    float* A    = (float*)(smem + 512);                // X then H2 (bufA)
    float* H1   = (float*)(smem + 33792);              // bufB
    float* pmax = (float*)(smem + 33792 + 8320);       // 4*128 floats

    const int g = (b << 10) + t;
    const float* bxp = xyz + (size_t)b * NN * 3;
    const float* bfp = features + (size_t)b * NN * NC;

    // wait for the centroid's index
    int v = __hip_atomic_load(idxbuf + g, __ATOMIC_RELAXED,
                              __HIP_MEMORY_SCOPE_AGENT);
    while (v < 0) {
        __builtin_amdgcn_s_sleep(8);
        v = __hip_atomic_load(idxbuf + g, __ATOMIC_RELAXED,
                              __HIP_MEMORY_SCOPE_AGENT);
    }
    const float cx = bxp[v * 3 + 0];
    const float cy = bxp[v * 3 + 1];
    const float cz = bxp[v * 3 + 2];

    // ---- ball query (wave 0 only; identical semantics) --------------------
    if (wave == 0) {
        int have = 0;
        for (int ch = 0; ch < NN / 64 && have < NSAMPLE; ++ch) {
            int j = ch * 64 + lane;
            float x = bxp[j * 3 + 0], y = bxp[j * 3 + 1], z = bxp[j * 3 + 2];
            float d2 = d2_exact(x, y, z, cx, cy, cz);
            bool hit = d2 < 0.04f;
            unsigned long long m = __ballot(hit);
            int pos = have + __popcll(m & ((1ull << lane) - 1ull));
            if (hit && pos < NSAMPLE) sel[pos] = j;
            have += __popcll(m);
        }
        int nsel = have < NSAMPLE ? have : NSAMPLE;
        int first = sel[0];
        if (lane < NSAMPLE && lane >= nsel) sel[lane] = first;
    }
    __syncthreads();

    // ---- gather X = [rel_xyz(3) | features(32)]: 8 threads/sample ---------
    {
        int s = tid >> 3, h = tid & 7;
        int row = sel[s];
        float4 v4 = *(const float4*)(bfp + (size_t)row * NC + h * 4);
        int base = s * XS + 3 + h * 4;
        A[base + 0] = v4.x; A[base + 1] = v4.y;
        A[base + 2] = v4.z; A[base + 3] = v4.w;
        if (h == 0) {
            A[s * XS + 0] = __fsub_rn(bxp[row * 3 + 0], cx);
            A[s * XS + 1] = __fsub_rn(bxp[row * 3 + 1], cy);
            A[s * XS + 2] = __fsub_rn(bxp[row * 3 + 2], cz);
        }
    }
    __syncthreads();

    const int sample = tid >> 3;   // 0..31, one per thread
    const int og = tid & 7;

    // ---- layer 1: 35 -> 64 -------------------------------------------------
    {
        float acc[8];
#pragma unroll
        for (int o = 0; o < 8; ++o) acc[o] = 0.f;
        for (int c = 0; c < 35; ++c) {
            float xv = A[sample * XS + c];
            const float* wr = w1 + c * 64 + og * 8;
            float4 wa = *(const float4*)(wr);
            float4 wb = *(const float4*)(wr + 4);
            float w8[8] = {wa.x, wa.y, wa.z, wa.w, wb.x, wb.y, wb.z, wb.w};
#pragma unroll
            for (int o = 0; o < 8; ++o) acc[o] += xv * w8[o];
        }
        float4 ba = *(const float4*)(b1 + og * 8);
        float4 bb = *(const float4*)(b1 + og * 8 + 4);
        float bias[8] = {ba.x, ba.y, ba.z, ba.w, bb.x, bb.y, bb.z, bb.w};
#pragma unroll
        for (int o = 0; o < 8; ++o)
            H1[sample * HS + og * 8 + o] = fmaxf(acc[o] + bias[o], 0.f);
    }
    __syncthreads();

    // ---- layer 2: 64 -> 64 -------------------------------------------------
    {
        float acc[8];
#pragma unroll
        for (int o = 0; o < 8; ++o) acc[o] = 0.f;
        for (int c = 0; c < 64; ++c) {
            float xv = H1[sample * HS + c];
            const float* wr = w2 + c * 64 + og * 8;
            float4 wa = *(const float4*)(wr);
            float4 wb = *(const float4*)(wr + 4);
            float w8[8] = {wa.x, wa.y, wa.z, wa.w, wb.x, wb.y, wb.z, wb.w};
#pragma unroll
            for (int o = 0; o < 8; ++o) acc[o] += xv * w8[o];
        }
        float4 ba = *(const float4*)(b2 + og * 8);
        float4 bb = *(const float4*)(b2 + og * 8 + 4);
        float bias[8] = {ba.x, ba.y, ba.z, ba.w, bb.x, bb.y, bb.z, bb.w};
#pragma unroll
        for (int o = 0; o < 8; ++o)
            A[sample * HS + og * 8 + o] = fmaxf(acc[o] + bias[o], 0.f);
    }
    __syncthreads();

    // ---- layer 3: 64 -> 128, maxpool over 32 samples -----------------------
    {
        float acc[16];
#pragma unroll
        for (int o = 0; o < 16; ++o) acc[o] = 0.f;
        for (int c = 0; c < 64; ++c) {
            float xv = A[sample * HS + c];
            const float* wr = w3 + c * 128 + og * 16;
            float4 wq[4];
#pragma unroll
            for (int q = 0; q < 4; ++q) wq[q] = *(const float4*)(wr + q * 4);
            float w16[16] = {wq[0].x, wq[0].y, wq[0].z, wq[0].w,
                             wq[1].x, wq[1].y, wq[1].z, wq[1].w,
                             wq[2].x, wq[2].y, wq[2].z, wq[2].w,
                             wq[3].x, wq[3].y, wq[3].z, wq[3].w};
#pragma unroll
            for (int o = 0; o < 16; ++o) acc[o] += xv * w16[o];
        }
        // wave-level maxpool over this wave's 8 samples (shfl tree spans
        // lane>>3), then 4-way cross-wave combine in LDS.
        float m[16];
#pragma unroll
        for (int o = 0; o < 16; ++o) m[o] = acc[o];
#pragma unroll
        for (int off = 8; off <= 32; off <<= 1)
#pragma unroll
            for (int o = 0; o < 16; ++o) m[o] = fmaxf(m[o], __shfl_xor(m[o], off));
        if (lane < 8) {
#pragma unroll
            for (int o = 0; o < 16; ++o)
                pmax[wave * 128 + (lane & 7) * 16 + o] = m[o];
        }
    }
    __syncthreads();

    if (tid < 8) {
        int oo = tid;   // og
        float4 bq[4];
#pragma unroll
        for (int q = 0; q < 4; ++q) bq[q] = *(const float4*)(b3 + oo * 16 + q * 4);
        float bias[16] = {bq[0].x, bq[0].y, bq[0].z, bq[0].w,
                          bq[1].x, bq[1].y, bq[1].z, bq[1].w,
                          bq[2].x, bq[2].y, bq[2].z, bq[2].w,
                          bq[3].x, bq[3].y, bq[3].z, bq[3].w};
#pragma unroll
        for (int o = 0; o < 16; ++o) {
            float mv = fmaxf(fmaxf(pmax[0 * 128 + oo * 16 + o],
                                   pmax[1 * 128 + oo * 16 + o]),
                             fmaxf(pmax[2 * 128 + oo * 16 + o],
                                   pmax[3 * 128 + oo * 16 + o]));
            float val = fmaxf(mv + bias[o], 0.f);
            out_feat[((size_t)b * 128 + oo * 16 + o) * NPOINT + t] = val;
        }
    }
}

__global__ __launch_bounds__(256, 1) void fused_kernel(
    const float* __restrict__ xyz, const float* __restrict__ normal,
    const float* __restrict__ features,
    const float* __restrict__ w1, const float* __restrict__ b1,
    const float* __restrict__ w2, const float* __restrict__ b2,
    const float* __restrict__ w3, const float* __restrict__ b3,
    float* __restrict__ out_xyz, float* __restrict__ out_normal,
    float* __restrict__ out_feat, int* __restrict__ idxbuf) {

    __shared__ __align__(16) char smem[SMEM_BYTES];

    if (blockIdx.x < NB) {
        // ================= producer: FPS (round-4 code, unchanged) =========
        unsigned long long (*redk)[4] = (unsigned long long (*)[4])(smem);
        int*   sel_hist = (int*)(smem + 64);
        float* sxyz     = (float*)(smem + 64 + 4096);

        const int b = blockIdx.x;
        const float* bx = xyz + (size_t)b * NN * 3;
        const int tid = threadIdx.x;
        const int lane = tid & 63;
        const int wave = tid >> 6;   // 0..3
        int* idxg = idxbuf + (b << 10);

        float px[FPS_K], py[FPS_K], pz[FPS_K], dist[FPS_K];
#pragma unroll
        for (int k = 0; k < FPS_K; ++k) {
            int p = tid + k * FPS_T;
            float x = bx[p * 3 + 0];
            float y = bx[p * 3 + 1];
            float z = bx[p * 3 + 2];
            px[k] = x; py[k] = y; pz[k] = z;
            sxyz[p * 3 + 0] = x;
            sxyz[p * 3 + 1] = y;
            sxyz[p * 3 + 2] = z;
            dist[k] = 1e10f;
        }
        // Pin the coordinate arrays (pre-loop only): opaque asm stops the
        // compiler from sinking the global loads into the hot loop.
#pragma unroll
        for (int k = 0; k < FPS_K; ++k) {
            asm volatile("" : "+v"(px[k]), "+v"(py[k]), "+v"(pz[k]));
        }

        int cur = 0;
        float lx = bx[0], ly = bx[1], lz = bx[2];

        for (int it = 0; it < NPOINT; ++it) {
            const int par = it & 1;
            if (tid == 0) sel_hist[it] = cur;

            // 4 independent argmax chains over contiguous k-ranges (dep
            // depth 8). Lower chain owns lower k; strict > keeps first
            // occurrence.
            float bv[4] = {-1.0f, -1.0f, -1.0f, -1.0f};
            int bk[4] = {0, 0, 0, 0};
#pragma unroll
            for (int k = 0; k < FPS_K; ++k) {
                const int c = k >> 3;
                float d = d2_exact(px[k], py[k], pz[k], lx, ly, lz);
                float nd = fminf(dist[k], d);
                dist[k] = nd;
                bool gt = nd > bv[c];       // strict >: lowest k on ties
                bv[c] = gt ? nd : bv[c];
                bk[c] = gt ? k : bk[c];
            }
            bool g1 = bv[1] > bv[0];
            float v01 = g1 ? bv[1] : bv[0];
            int   k01 = g1 ? bk[1] : bk[0];
            bool g3 = bv[3] > bv[2];
            float v23 = g3 ? bv[3] : bv[2];
            int   k23 = g3 ? bk[3] : bk[2];
            bool gf = v23 > v01;
            float bvf = gf ? v23 : v01;
            int   bkf = gf ? k23 : k01;

            int bp = tid + (bkf << 8);      // FPS_T == 256
            unsigned long long key =
                ((unsigned long long)__float_as_uint(bvf) << 32) |
                (unsigned)(~bp);

            // wave max via DPP (each stage: 2 dpp + 1 v_max_f64);
            // cross-wave via 4 LDS slots, parity dbuf.
            key = kmax64(key, dpp_k<0x111, 0xf>(key));
            key = kmax64(key, dpp_k<0x112, 0xf>(key));
            key = kmax64(key, dpp_k<0x114, 0xf>(key));
            key = kmax64(key, dpp_k<0x118, 0xf>(key));
            key = kmax64(key, dpp_k<0x142, 0xa>(key));
            key = kmax64(key, dpp_k<0x143, 0xc>(key));
            if (lane == 63) redk[par][wave] = key;
            barrier_lds_only();

            unsigned long long g =
                kmax64(kmax64(redk[par][0], redk[par][1]),
                       kmax64(redk[par][2], redk[par][3]));
            int p = (int)(~(unsigned)(g & 0xffffffffULL));
            p = __builtin_amdgcn_readfirstlane(p);   // uniform
            lx = sxyz[p * 3 + 0];
            ly = sxyz[p * 3 + 1];
            lz = sxyz[p * 3 + 2];
            cur = p;

            // publish chunk of 16 selected indices (fire-and-forget agent
            // atomics; never drained inside the loop).
            if (((it & 15) == 15) && tid < 16) {
                int t = (it & ~15) + tid;
                __hip_atomic_store(idxg + t, sel_hist[t], __ATOMIC_RELAXED,
                                   __HIP_MEMORY_SCOPE_AGENT);
            }
        }
        __syncthreads();

        // final gather of new_xyz / new_normal (host-visible outputs)
        const float* bn = normal + (size_t)b * NN * 3;
        for (int t = tid; t < NPOINT; t += FPS_T) {
            int i = sel_hist[t];
            size_t o = ((size_t)b * NPOINT + t) * 3;
            out_xyz[o + 0] = sxyz[i * 3 + 0];
            out_xyz[o + 1] = sxyz[i * 3 + 1];
            out_xyz[o + 2] = sxyz[i * 3 + 2];
            out_normal[o + 0] = bn[i * 3 + 0];
            out_normal[o + 1] = bn[i * 3 + 1];
            out_normal[o + 2] = bn[i * 3 + 2];
        }
        __syncthreads();

        // ---- join the tail: consume centroid (b, 1023) cooperatively ------
        // k2 = 7936 + 248 + b = 8184 + b -> batch (8184+b)&7 == b, t == 1023
        // (the centroid this very block published moments ago).
        coop_centroid(b, NPOINT - 1, xyz, features, w1, b1, w2, b2, w3, b3,
                      out_feat, idxbuf, smem, tid);
    } else {
        // ================= consumer: bulk wave-per-centroid ================
        int*   sel_all  = (int*)smem;                    // [4][32]
        float* bufA_all = (float*)(smem + 512);          // [4][2080]
        float* bufB_all = (float*)(smem + 33792);        // [4][2080]

        const int cb = blockIdx.x - NB;      // 0..247
        const int wave = threadIdx.x >> 6;   // 0..3
        const int lane = threadIdx.x & 63;
        int*   sel = sel_all + wave * 32;
        float* XA  = bufA_all + wave * 2080;
        float* XB  = bufB_all + wave * 2080;

        for (int pass = 0; pass < NBULK; ++pass) {
            int k = pass * SLOTS_PER_PASS + (cb * K2_WAVES + wave);  // < 7936
            const int b = k & 7;
            const int t = k >> 3;
            const int g = (b << 10) + t;
            const int p = t;
            const float* bxp = xyz + (size_t)b * NN * 3;
            const float* bfp = features + (size_t)b * NN * NC;

            // wait until the producer has published this centroid's index
            int v = __hip_atomic_load(idxbuf + g, __ATOMIC_RELAXED,
                                      __HIP_MEMORY_SCOPE_AGENT);
            while (v < 0) {
                __builtin_amdgcn_s_sleep(8);
                v = __hip_atomic_load(idxbuf + g, __ATOMIC_RELAXED,
                                      __HIP_MEMORY_SCOPE_AGENT);
            }
            const float cx = bxp[v * 3 + 0];
            const float cy = bxp[v * 3 + 1];
            const float cz = bxp[v * 3 + 2];

            // ---- ball query: first NSAMPLE hits in ascending index order --
            int have = 0;
            for (int ch = 0; ch < NN / 64 && have < NSAMPLE; ++ch) {
                int j = ch * 64 + lane;
                float x = bxp[j * 3 + 0], y = bxp[j * 3 + 1], z = bxp[j * 3 + 2];
                float d2 = d2_exact(x, y, z, cx, cy, cz);
                bool hit = d2 < 0.04f;   // strict f32 compare
                unsigned long long m = __ballot(hit);
                int pos = have + __popcll(m & ((1ull << lane) - 1ull));
                if (hit && pos < NSAMPLE) sel[pos] = j;
                have += __popcll(m);
            }
            __syncthreads();
            int nsel = have < NSAMPLE ? have : NSAMPLE;
            int first = sel[0];   // centroid itself always hits -> nsel >= 1
            if (lane < NSAMPLE && lane >= nsel) sel[lane] = first;
            __syncthreads();

            // ---- gather X = [rel_xyz(3) | features(32)] into LDS ----------
            {
                int s = lane >> 1, h = lane & 1;
                int row = sel[s];
                const float* fr = bfp + (size_t)row * NC + h * 16;
#pragma unroll
                for (int q = 0; q < 4; ++q) {
                    float4 vv = *(const float4*)(fr + q * 4);
                    int base = s * XS + 3 + h * 16 + q * 4;
                    XA[base + 0] = vv.x; XA[base + 1] = vv.y;
                    XA[base + 2] = vv.z; XA[base + 3] = vv.w;
                }
                if (h == 0) {
                    XA[s * XS + 0] = __fsub_rn(bxp[row * 3 + 0], cx);
                    XA[s * XS + 1] = __fsub_rn(bxp[row * 3 + 1], cy);
                    XA[s * XS + 2] = __fsub_rn(bxp[row * 3 + 2], cz);
                }
            }
            __syncthreads();

            const int sg = lane >> 3;   // 0..7 -> samples sg*4 .. sg*4+3
            const int og = lane & 7;    // output-channel group

            // ---- layer 1: 35 -> 64 ---------------------------------------
            {
                float acc[4][8];
#pragma unroll
                for (int j = 0; j < 4; ++j)
#pragma unroll
                    for (int o = 0; o < 8; ++o) acc[j][o] = 0.f;
                for (int c = 0; c < 35; ++c) {
                    float xv[4];
#pragma unroll
                    for (int j = 0; j < 4; ++j) xv[j] = XA[(sg * 4 + j) * XS + c];
                    const float* wr = w1 + c * 64 + og * 8;
                    float4 wa = *(const float4*)(wr);
                    float4 wb = *(const float4*)(wr + 4);
                    float w8[8] = {wa.x, wa.y, wa.z, wa.w, wb.x, wb.y, wb.z, wb.w};
#pragma unroll
                    for (int j = 0; j < 4; ++j)
#pragma unroll
                        for (int o = 0; o < 8; ++o) acc[j][o] += xv[j] * w8[o];
                }
                float4 ba = *(const float4*)(b1 + og * 8);
                float4 bb = *(const float4*)(b1 + og * 8 + 4);
                float bias[8] = {ba.x, ba.y, ba.z, ba.w, bb.x, bb.y, bb.z, bb.w};
#pragma unroll
                for (int j = 0; j < 4; ++j)
#pragma unroll
                    for (int o = 0; o < 8; ++o)
                        XB[(sg * 4 + j) * HS + og * 8 + o] =
                            fmaxf(acc[j][o] + bias[o], 0.f);
            }
            __syncthreads();

            // ---- layer 2: 64 -> 64 ---------------------------------------
            {
                float acc[4][8];
#pragma unroll
                for (int j = 0; j < 4; ++j)
#pragma unroll
                    for (int o = 0; o < 8; ++o) acc[j][o] = 0.f;
                for (int c = 0; c < 64; ++c) {
                    float xv[4];
#pragma unroll
                    for (int j = 0; j < 4; ++j) xv[j] = XB[(sg * 4 + j) * HS + c];
                    const float* wr = w2 + c * 64 + og * 8;
                    float4 wa = *(const float4*)(wr);
                    float4 wb = *(const float4*)(wr + 4);
                    float w8[8] = {wa.x, wa.y, wa.z, wa.w, wb.x, wb.y, wb.z, wb.w};
#pragma unroll
                    for (int j = 0; j < 4; ++j)
#pragma unroll
                        for (int o = 0; o < 8; ++o) acc[j][o] += xv[j] * w8[o];
                }
                float4 ba = *(const float4*)(b2 + og * 8);
                float4 bb = *(const float4*)(b2 + og * 8 + 4);
                float bias[8] = {ba.x, ba.y, ba.z, ba.w, bb.x, bb.y, bb.z, bb.w};
#pragma unroll
                for (int j = 0; j < 4; ++j)
#pragma unroll
                    for (int o = 0; o < 8; ++o)
                        XA[(sg * 4 + j) * HS + og * 8 + o] =
                            fmaxf(acc[j][o] + bias[o], 0.f);
            }
            __syncthreads();

            // ---- layer 3: 64 -> 128, maxpool over 32 samples -------------
            {
                float acc[4][16];
#pragma unroll
                for (int j = 0; j < 4; ++j)
#pragma unroll
                    for (int o = 0; o < 16; ++o) acc[j][o] = 0.f;
                for (int c = 0; c < 64; ++c) {
                    float xv[4];
#pragma unroll
                    for (int j = 0; j < 4; ++j) xv[j] = XA[(sg * 4 + j) * HS + c];
                    const float* wr = w3 + c * 128 + og * 16;
                    float4 wq[4];
#pragma unroll
                    for (int q = 0; q < 4; ++q) wq[q] = *(const float4*)(wr + q * 4);
                    float w16[16] = {wq[0].x, wq[0].y, wq[0].z, wq[0].w,
                                     wq[1].x, wq[1].y, wq[1].z, wq[1].w,
                                     wq[2].x, wq[2].y, wq[2].z, wq[2].w,
                                     wq[3].x, wq[3].y, wq[3].z, wq[3].w};
#pragma unroll
                    for (int j = 0; j < 4; ++j)
#pragma unroll
                        for (int o = 0; o < 16; ++o) acc[j][o] += xv[j] * w16[o];
                }
                float m[16];
#pragma unroll
                for (int o = 0; o < 16; ++o) {
                    float t0 = fmaxf(acc[0][o], acc[1][o]);
                    float t1 = fmaxf(acc[2][o], acc[3][o]);
                    m[o] = fmaxf(t0, t1);
                }
#pragma unroll
                for (int off = 8; off <= 32; off <<= 1)
#pragma unroll
                    for (int o = 0; o < 16; ++o)
                        m[o] = fmaxf(m[o], __shfl_xor(m[o], off));
                if (sg == 0) {
                    float4 bq[4];
#pragma unroll
                    for (int q = 0; q < 4; ++q)
                        bq[q] = *(const float4*)(b3 + og * 16 + q * 4);
                    float bias[16] = {bq[0].x, bq[0].y, bq[0].z, bq[0].w,
                                      bq[1].x, bq[1].y, bq[1].z, bq[1].w,
                                      bq[2].x, bq[2].y, bq[2].z, bq[2].w,
                                      bq[3].x, bq[3].y, bq[3].z, bq[3].w};
#pragma unroll
                    for (int o = 0; o < 16; ++o) {
                        float val = fmaxf(m[o] + bias[o], 0.f);
                        out_feat[((size_t)b * 128 + og * 16 + o) * NPOINT + p] = val;
                    }
                }
            }
        }
        __syncthreads();

        // ---- final tail: one block per centroid, 4-wave cooperative -------
        // consumer cb takes k2 = 7936 + cb -> b = cb&7, t = 992 + (cb>>3).
        {
            int k2 = NBULK * SLOTS_PER_PASS + cb;
            coop_centroid(k2 & 7, k2 >> 3, xyz, features, w1, b1, w2, b2,
                          w3, b3, out_feat, idxbuf, smem, threadIdx.x);
        }
    }
}

// ---------------------------------------------------------------------------
extern "C" void kernel_launch(void* const* d_in, const int* in_sizes, int n_in,
                              void* d_out, int out_size, void* d_ws, size_t ws_size,
                              hipStream_t stream) {
    const float* xyz      = (const float*)d_in[0];
    const float* normal   = (const float*)d_in[1];
    const float* features = (const float*)d_in[2];
    const float* w1 = (const float*)d_in[3];
    const float* b1 = (const float*)d_in[4];
    const float* w2 = (const float*)d_in[5];
    const float* b2 = (const float*)d_in[6];
    const float* w3 = (const float*)d_in[7];
    const float* b3 = (const float*)d_in[8];

    float* out        = (float*)d_out;
    float* out_xyz    = out;                       // (8,1024,3)
    float* out_normal = out + NB * NPOINT * 3;     // (8,1024,3)
    float* out_feat   = out + 2 * NB * NPOINT * 3; // (8,128,1024)
    int*   idxbuf     = (int*)d_ws;                // 8192 ints

    // 0xFF bytes -> every int == -1 (the "unpublished" sentinel).
    hipMemsetAsync(idxbuf, 0xFF, NB * NPOINT * sizeof(int), stream);

    hipLaunchKernelGGL(fused_kernel, dim3(NBLK), dim3(256), 0, stream,
                       xyz, normal, features, w1, b1, w2, b2, w3, b3,
                       out_xyz, out_normal, out_feat, idxbuf);
}

// Round 7
// 1018.815 us; speedup vs baseline: 1.1065x; 1.0070x over previous
//
#include <hip/hip_runtime.h>

#define NB 8
#define NN 8192
#define NC 32
#define NPOINT 1024
#define NSAMPLE 32

// Exact round-to-nearest distance, no fma contraction: matches numpy
// ((dx*dx + dy*dy) + dz*dz) bitwise.
__device__ __forceinline__ float d2_exact(float ax, float ay, float az,
                                          float bx, float by, float bz) {
    float dx = __fsub_rn(ax, bx);
    float dy = __fsub_rn(ay, by);
    float dz = __fsub_rn(az, bz);
    return __fadd_rn(__fadd_rn(__fmul_rn(dx, dx), __fmul_rn(dy, dy)),
                     __fmul_rn(dz, dz));
}

// ---------------------------------------------------------------------------
// Round-10: SINGLE-VARIABLE A/B vs the best measured config (round-4:
// fused 970us / total 1025us). Kernel code is byte-identical to round-4.
// Only change: hipMemsetAsync -> tiny init kernel.
//
// Evidence: total-minus-fused gap by init mechanism:
//   round 0 (no init, two plain kernel nodes):      gap ~3us
//   rounds 4/6 (hipMemsetAsync node + plain launch): gap 55/48us
//   rounds 2/3 (init kernel + COOPERATIVE launch):   gap 70/78us
// A 32KB memset executes in ~2us, so the ~50us is node overhead: under
// graph capture hipMemsetAsync appears to materialize as an expensive node.
// Plain kernel nodes are ~free (round 0). So: init via a 2us kernel node.
// Falsifier: if total stays >=1015, the gap is dispatch ramp of the
// 256-block/102KB-LDS kernel and the structure is converged.
//
// (Producer retired at ~2200 cyc/iter after 7 variants: pk-math regresses
// — v_pk_f32 is 2-pass on gfx950; in-loop pins regress; reduce rewrites
// neutral-to-negative. Consumer tail restructure (round 6 coop) neutral:
// critical path = last bulk publish + one centroid, already minimal.)
// ---------------------------------------------------------------------------
#define FPS_T 256
#define FPS_K (NN / FPS_T)   // 32 points per thread
#define NCONS 248
#define NBLK (NB + NCONS)    // 256 blocks, 1 per CU
#define K2_WAVES 4
#define SLOTS_PER_PASS (NCONS * K2_WAVES)                              // 992
#define NPASS ((NB * NPOINT + SLOTS_PER_PASS - 1) / SLOTS_PER_PASS)    // 9

#define XS 37   // X row stride (35 cols + pad)
#define HS 65   // H row stride (64 cols + pad)

// shared-memory union layout (bytes):
//   producer: redk[2][4] ull @0 (64), sel_hist[1024] int @64 (4096),
//             sxyz[8192*3] f32 @4160 (98304)  -> 102464 used
//   consumer: sel_s[4][32] int @0 (512), bufA[4][2080] f32 @512 (33280),
//             bufB[4][2080] f32 @33792 (33280) -> 67072 used
// 102464 > 81920 guarantees 1 block/CU (2 blocks would exceed 160 KB).
#define SMEM_BYTES 102464

// u64 max implemented as v_max_f64 — valid for our key domain: high word is
// f32 bits of a dist in [0, 1e10] => non-negative finite f64 pattern, where
// u64 order == f64 order (denormals included; f64 never flushes).
__device__ __forceinline__ unsigned long long kmax64(unsigned long long a,
                                                     unsigned long long b) {
    double r = fmax(__longlong_as_double((long long)a),
                    __longlong_as_double((long long)b));
    return (unsigned long long)__double_as_longlong(r);
}

template <int CTRL, int RM>
__device__ __forceinline__ unsigned long long dpp_k(unsigned long long k) {
    unsigned hi = (unsigned)__builtin_amdgcn_update_dpp(
        0, (int)(k >> 32), CTRL, RM, 0xf, true);
    unsigned lo = (unsigned)__builtin_amdgcn_update_dpp(
        0, (int)(k & 0xffffffffULL), CTRL, RM, 0xf, true);
    return ((unsigned long long)hi << 32) | lo;
}

// Workgroup barrier that drains LDS ops only (no vmcnt(0)): keeps the
// fire-and-forget publish atomics off the barrier critical path.
__device__ __forceinline__ void barrier_lds_only() {
    asm volatile("s_waitcnt lgkmcnt(0)\n\ts_barrier" ::: "memory");
}

__global__ __launch_bounds__(256, 1) void fused_kernel(
    const float* __restrict__ xyz, const float* __restrict__ normal,
    const float* __restrict__ features,
    const float* __restrict__ w1, const float* __restrict__ b1,
    const float* __restrict__ w2, const float* __restrict__ b2,
    const float* __restrict__ w3, const float* __restrict__ b3,
    float* __restrict__ out_xyz, float* __restrict__ out_normal,
    float* __restrict__ out_feat, int* __restrict__ idxbuf) {

    __shared__ __align__(16) char smem[SMEM_BYTES];

    if (blockIdx.x < NB) {
        // ================= producer: FPS ===================================
        unsigned long long (*redk)[4] = (unsigned long long (*)[4])(smem);
        int*   sel_hist = (int*)(smem + 64);
        float* sxyz     = (float*)(smem + 64 + 4096);

        const int b = blockIdx.x;
        const float* bx = xyz + (size_t)b * NN * 3;
        const int tid = threadIdx.x;
        const int lane = tid & 63;
        const int wave = tid >> 6;   // 0..3
        int* idxg = idxbuf + (b << 10);

        float px[FPS_K], py[FPS_K], pz[FPS_K], dist[FPS_K];
#pragma unroll
        for (int k = 0; k < FPS_K; ++k) {
            int p = tid + k * FPS_T;
            float x = bx[p * 3 + 0];
            float y = bx[p * 3 + 1];
            float z = bx[p * 3 + 2];
            px[k] = x; py[k] = y; pz[k] = z;
            sxyz[p * 3 + 0] = x;
            sxyz[p * 3 + 1] = y;
            sxyz[p * 3 + 2] = z;
            dist[k] = 1e10f;
        }
        // Pin the coordinate arrays (pre-loop only): opaque asm stops the
        // compiler from sinking the global loads into the hot loop.
#pragma unroll
        for (int k = 0; k < FPS_K; ++k) {
            asm volatile("" : "+v"(px[k]), "+v"(py[k]), "+v"(pz[k]));
        }

        int cur = 0;
        float lx = bx[0], ly = bx[1], lz = bx[2];

        for (int it = 0; it < NPOINT; ++it) {
            const int par = it & 1;
            if (tid == 0) sel_hist[it] = cur;

            // 4 independent argmax chains over contiguous k-ranges (dep
            // depth 8). Lower chain owns lower k; strict > keeps first
            // occurrence.
            float bv[4] = {-1.0f, -1.0f, -1.0f, -1.0f};
            int bk[4] = {0, 0, 0, 0};
#pragma unroll
            for (int k = 0; k < FPS_K; ++k) {
                const int c = k >> 3;
                float d = d2_exact(px[k], py[k], pz[k], lx, ly, lz);
                float nd = fminf(dist[k], d);
                dist[k] = nd;
                bool gt = nd > bv[c];       // strict >: lowest k on ties
                bv[c] = gt ? nd : bv[c];
                bk[c] = gt ? k : bk[c];
            }
            bool g1 = bv[1] > bv[0];
            float v01 = g1 ? bv[1] : bv[0];
            int   k01 = g1 ? bk[1] : bk[0];
            bool g3 = bv[3] > bv[2];
            float v23 = g3 ? bv[3] : bv[2];
            int   k23 = g3 ? bk[3] : bk[2];
            bool gf = v23 > v01;
            float bvf = gf ? v23 : v01;
            int   bkf = gf ? k23 : k01;

            int bp = tid + (bkf << 8);      // FPS_T == 256
            unsigned long long key =
                ((unsigned long long)__float_as_uint(bvf) << 32) |
                (unsigned)(~bp);

            // wave max via DPP (each stage: 2 dpp + 1 v_max_f64);
            // cross-wave via 4 LDS slots, parity dbuf.
            key = kmax64(key, dpp_k<0x111, 0xf>(key));
            key = kmax64(key, dpp_k<0x112, 0xf>(key));
            key = kmax64(key, dpp_k<0x114, 0xf>(key));
            key = kmax64(key, dpp_k<0x118, 0xf>(key));
            key = kmax64(key, dpp_k<0x142, 0xa>(key));
            key = kmax64(key, dpp_k<0x143, 0xc>(key));
            if (lane == 63) redk[par][wave] = key;
            barrier_lds_only();

            unsigned long long g =
                kmax64(kmax64(redk[par][0], redk[par][1]),
                       kmax64(redk[par][2], redk[par][3]));
            int p = (int)(~(unsigned)(g & 0xffffffffULL));
            p = __builtin_amdgcn_readfirstlane(p);   // uniform
            // winner coords from LDS broadcast (uniform addr) — keeps the
            // L2 round trip off the serial path.
            lx = sxyz[p * 3 + 0];
            ly = sxyz[p * 3 + 1];
            lz = sxyz[p * 3 + 2];
            cur = p;

            // publish chunk of 16 selected indices (fire-and-forget agent
            // atomics; never drained inside the loop).
            if (((it & 15) == 15) && tid < 16) {
                int t = (it & ~15) + tid;
                __hip_atomic_store(idxg + t, sel_hist[t], __ATOMIC_RELAXED,
                                   __HIP_MEMORY_SCOPE_AGENT);
            }
        }
        __syncthreads();

        // final gather of new_xyz / new_normal (host-visible outputs)
        const float* bn = normal + (size_t)b * NN * 3;
        for (int t = tid; t < NPOINT; t += FPS_T) {
            int i = sel_hist[t];
            size_t o = ((size_t)b * NPOINT + t) * 3;
            out_xyz[o + 0] = sxyz[i * 3 + 0];
            out_xyz[o + 1] = sxyz[i * 3 + 1];
            out_xyz[o + 2] = sxyz[i * 3 + 2];
            out_normal[o + 0] = bn[i * 3 + 0];
            out_normal[o + 1] = bn[i * 3 + 1];
            out_normal[o + 2] = bn[i * 3 + 2];
        }
    } else {
        // ================= consumer: ball query + MLP + maxpool ============
        int*   sel_all  = (int*)smem;                    // [4][32]
        float* bufA_all = (float*)(smem + 512);          // [4][2080]
        float* bufB_all = (float*)(smem + 33792);        // [4][2080]

        const int cb = blockIdx.x - NB;      // 0..247
        const int wave = threadIdx.x >> 6;   // 0..3
        const int lane = threadIdx.x & 63;
        int*   sel = sel_all + wave * 32;
        float* XA  = bufA_all + wave * 2080;
        float* XB  = bufB_all + wave * 2080;

        for (int pass = 0; pass < NPASS; ++pass) {
            int k = pass * SLOTS_PER_PASS + (cb * K2_WAVES + wave);
            if (k >= NB * NPOINT) k -= NB * NPOINT;  // dummies redo early
                                                     // centroids (identical
                                                     // rewrites: benign)
            const int b = k & 7;
            const int t = k >> 3;
            const int g = (b << 10) + t;
            const int p = t;
            const float* bxp = xyz + (size_t)b * NN * 3;
            const float* bfp = features + (size_t)b * NN * NC;

            // wait until the producer has published this centroid's index
            int v = __hip_atomic_load(idxbuf + g, __ATOMIC_RELAXED,
                                      __HIP_MEMORY_SCOPE_AGENT);
            while (v < 0) {
                __builtin_amdgcn_s_sleep(8);
                v = __hip_atomic_load(idxbuf + g, __ATOMIC_RELAXED,
                                      __HIP_MEMORY_SCOPE_AGENT);
            }
            const float cx = bxp[v * 3 + 0];
            const float cy = bxp[v * 3 + 1];
            const float cz = bxp[v * 3 + 2];

            // ---- ball query: first NSAMPLE hits in ascending index order --
            int have = 0;
            for (int ch = 0; ch < NN / 64 && have < NSAMPLE; ++ch) {
                int j = ch * 64 + lane;
                float x = bxp[j * 3 + 0], y = bxp[j * 3 + 1], z = bxp[j * 3 + 2];
                float d2 = d2_exact(x, y, z, cx, cy, cz);
                bool hit = d2 < 0.04f;   // strict f32 compare
                unsigned long long m = __ballot(hit);
                int pos = have + __popcll(m & ((1ull << lane) - 1ull));
                if (hit && pos < NSAMPLE) sel[pos] = j;
                have += __popcll(m);
            }
            __syncthreads();
            int nsel = have < NSAMPLE ? have : NSAMPLE;
            int first = sel[0];   // centroid itself always hits -> nsel >= 1
            if (lane < NSAMPLE && lane >= nsel) sel[lane] = first;
            __syncthreads();

            // ---- gather X = [rel_xyz(3) | features(32)] into LDS ----------
            {
                int s = lane >> 1, h = lane & 1;
                int row = sel[s];
                const float* fr = bfp + (size_t)row * NC + h * 16;
#pragma unroll
                for (int q = 0; q < 4; ++q) {
                    float4 vv = *(const float4*)(fr + q * 4);
                    int base = s * XS + 3 + h * 16 + q * 4;
                    XA[base + 0] = vv.x; XA[base + 1] = vv.y;
                    XA[base + 2] = vv.z; XA[base + 3] = vv.w;
                }
                if (h == 0) {
                    XA[s * XS + 0] = __fsub_rn(bxp[row * 3 + 0], cx);
                    XA[s * XS + 1] = __fsub_rn(bxp[row * 3 + 1], cy);
                    XA[s * XS + 2] = __fsub_rn(bxp[row * 3 + 2], cz);
                }
            }
            __syncthreads();

            const int sg = lane >> 3;   // 0..7 -> samples sg*4 .. sg*4+3
            const int og = lane & 7;    // output-channel group

            // ---- layer 1: 35 -> 64 ---------------------------------------
            {
                float acc[4][8];
#pragma unroll
                for (int j = 0; j < 4; ++j)
#pragma unroll
                    for (int o = 0; o < 8; ++o) acc[j][o] = 0.f;
                for (int c = 0; c < 35; ++c) {
                    float xv[4];
#pragma unroll
                    for (int j = 0; j < 4; ++j) xv[j] = XA[(sg * 4 + j) * XS + c];
                    const float* wr = w1 + c * 64 + og * 8;
                    float4 wa = *(const float4*)(wr);
                    float4 wb = *(const float4*)(wr + 4);
                    float w8[8] = {wa.x, wa.y, wa.z, wa.w, wb.x, wb.y, wb.z, wb.w};
#pragma unroll
                    for (int j = 0; j < 4; ++j)
#pragma unroll
                        for (int o = 0; o < 8; ++o) acc[j][o] += xv[j] * w8[o];
                }
                float4 ba = *(const float4*)(b1 + og * 8);
                float4 bb = *(const float4*)(b1 + og * 8 + 4);
                float bias[8] = {ba.x, ba.y, ba.z, ba.w, bb.x, bb.y, bb.z, bb.w};
#pragma unroll
                for (int j = 0; j < 4; ++j)
#pragma unroll
                    for (int o = 0; o < 8; ++o)
                        XB[(sg * 4 + j) * HS + og * 8 + o] =
                            fmaxf(acc[j][o] + bias[o], 0.f);
            }
            __syncthreads();

            // ---- layer 2: 64 -> 64 ---------------------------------------
            {
                float acc[4][8];
#pragma unroll
                for (int j = 0; j < 4; ++j)
#pragma unroll
                    for (int o = 0; o < 8; ++o) acc[j][o] = 0.f;
                for (int c = 0; c < 64; ++c) {
                    float xv[4];
#pragma unroll
                    for (int j = 0; j < 4; ++j) xv[j] = XB[(sg * 4 + j) * HS + c];
                    const float* wr = w2 + c * 64 + og * 8;
                    float4 wa = *(const float4*)(wr);
                    float4 wb = *(const float4*)(wr + 4);
                    float w8[8] = {wa.x, wa.y, wa.z, wa.w, wb.x, wb.y, wb.z, wb.w};
#pragma unroll
                    for (int j = 0; j < 4; ++j)
#pragma unroll
                        for (int o = 0; o < 8; ++o) acc[j][o] += xv[j] * w8[o];
                }
                float4 ba = *(const float4*)(b2 + og * 8);
                float4 bb = *(const float4*)(b2 + og * 8 + 4);
                float bias[8] = {ba.x, ba.y, ba.z, ba.w, bb.x, bb.y, bb.z, bb.w};
#pragma unroll
                for (int j = 0; j < 4; ++j)
#pragma unroll
                    for (int o = 0; o < 8; ++o)
                        XA[(sg * 4 + j) * HS + og * 8 + o] =
                            fmaxf(acc[j][o] + bias[o], 0.f);
            }
            __syncthreads();

            // ---- layer 3: 64 -> 128, maxpool over 32 samples -------------
            {
                float acc[4][16];
#pragma unroll
                for (int j = 0; j < 4; ++j)
#pragma unroll
                    for (int o = 0; o < 16; ++o) acc[j][o] = 0.f;
                for (int c = 0; c < 64; ++c) {
                    float xv[4];
#pragma unroll
                    for (int j = 0; j < 4; ++j) xv[j] = XA[(sg * 4 + j) * HS + c];
                    const float* wr = w3 + c * 128 + og * 16;
                    float4 wq[4];
#pragma unroll
                    for (int q = 0; q < 4; ++q) wq[q] = *(const float4*)(wr + q * 4);
                    float w16[16] = {wq[0].x, wq[0].y, wq[0].z, wq[0].w,
                                     wq[1].x, wq[1].y, wq[1].z, wq[1].w,
                                     wq[2].x, wq[2].y, wq[2].z, wq[2].w,
                                     wq[3].x, wq[3].y, wq[3].z, wq[3].w};
#pragma unroll
                    for (int j = 0; j < 4; ++j)
#pragma unroll
                        for (int o = 0; o < 16; ++o) acc[j][o] += xv[j] * w16[o];
                }
                float m[16];
#pragma unroll
                for (int o = 0; o < 16; ++o) {
                    float t0 = fmaxf(acc[0][o], acc[1][o]);
                    float t1 = fmaxf(acc[2][o], acc[3][o]);
                    m[o] = fmaxf(t0, t1);
                }
#pragma unroll
                for (int off = 8; off <= 32; off <<= 1)
#pragma unroll
                    for (int o = 0; o < 16; ++o)
                        m[o] = fmaxf(m[o], __shfl_xor(m[o], off));
                if (sg == 0) {
                    float4 bq[4];
#pragma unroll
                    for (int q = 0; q < 4; ++q)
                        bq[q] = *(const float4*)(b3 + og * 16 + q * 4);
                    float bias[16] = {bq[0].x, bq[0].y, bq[0].z, bq[0].w,
                                      bq[1].x, bq[1].y, bq[1].z, bq[1].w,
                                      bq[2].x, bq[2].y, bq[2].z, bq[2].w,
                                      bq[3].x, bq[3].y, bq[3].z, bq[3].w};
#pragma unroll
                    for (int o = 0; o < 16; ++o) {
                        float val = fmaxf(m[o] + bias[o], 0.f);
                        out_feat[((size_t)b * 128 + og * 16 + o) * NPOINT + p] = val;
                    }
                }
            }
            // bufA reread next pass only after the pass's early barriers.
        }
    }
}

// ---------------------------------------------------------------------------
// Tiny init kernel (plain kernel node ~2us; round 0 shows kernel nodes are
// ~free in the capture, unlike the ~50us hipMemsetAsync node).
__global__ void init_ws(int* __restrict__ idxbuf) {
    int i = blockIdx.x * blockDim.x + threadIdx.x;
    if (i < NB * NPOINT) idxbuf[i] = -1;
}

// ---------------------------------------------------------------------------
extern "C" void kernel_launch(void* const* d_in, const int* in_sizes, int n_in,
                              void* d_out, int out_size, void* d_ws, size_t ws_size,
                              hipStream_t stream) {
    const float* xyz      = (const float*)d_in[0];
    const float* normal   = (const float*)d_in[1];
    const float* features = (const float*)d_in[2];
    const float* w1 = (const float*)d_in[3];
    const float* b1 = (const float*)d_in[4];
    const float* w2 = (const float*)d_in[5];
    const float* b2 = (const float*)d_in[6];
    const float* w3 = (const float*)d_in[7];
    const float* b3 = (const float*)d_in[8];

    float* out        = (float*)d_out;
    float* out_xyz    = out;                       // (8,1024,3)
    float* out_normal = out + NB * NPOINT * 3;     // (8,1024,3)
    float* out_feat   = out + 2 * NB * NPOINT * 3; // (8,128,1024)
    int*   idxbuf     = (int*)d_ws;                // 8192 ints

    hipLaunchKernelGGL(init_ws, dim3(32), dim3(256), 0, stream, idxbuf);

    hipLaunchKernelGGL(fused_kernel, dim3(NBLK), dim3(256), 0, stream,
                       xyz, normal, features, w1, b1, w2, b2, w3, b3,
                       out_xyz, out_normal, out_feat, idxbuf);
}